// Round 9
// baseline (144.816 us; speedup 1.0000x reference)
//
#include <hip/hip_runtime.h>
#include <cstddef>
#include <cstdint>

// Problem constants: B=2, T=2048, C=1024, H=16, hs=64
#define B_N 2
#define T_N 2048
#define C_N 1024
#define H_N 16
#define HS_N 64
#define M_N (B_N * T_N)   // 4096

typedef __attribute__((ext_vector_type(8))) short bf16x8;   // 8 bf16 = 4 VGPRs
typedef __attribute__((ext_vector_type(4))) float f32x4;
typedef __attribute__((ext_vector_type(4))) unsigned int u32x4;
typedef __attribute__((ext_vector_type(2))) unsigned int u32x2;

// 0.125 (hs^-0.5) * log2(e): folded into Wq so attention uses exp2 directly
#define QSCALE 0.18033688011112042f

__device__ __forceinline__ ushort f2bf(float f) {
    union { float f; uint32_t u; } v; v.f = f;
    uint32_t r = v.u + 0x7fffu + ((v.u >> 16) & 1u);   // round-nearest-even
    return (ushort)(r >> 16);
}
// truncating pack of two P-values (P in [0,1], rel err ~2^-9 — validated)
__device__ __forceinline__ unsigned pack2_trunc(float a, float b) {
    union { float f; uint32_t u; } x, y; x.f = a; y.f = b;
    return (x.u >> 16) | (y.u & 0xFFFF0000u);
}

// async global->LDS, 16B per lane; lds base must be wave-uniform
#define GLL16(g, l)                                                         \
    __builtin_amdgcn_global_load_lds(                                       \
        (const __attribute__((address_space(1))) unsigned int*)(g),         \
        (__attribute__((address_space(3))) unsigned int*)(l), 16, 0, 0)

// ---------------------------------------------------------------------------
// Fused fp32->bf16 convert: x | Wq(*QSCALE) | Wp | Wk | Wv (one launch).
// ---------------------------------------------------------------------------
__global__ void cvt_all_kernel(const float* __restrict__ x,
                               const float* __restrict__ Wq,
                               const float* __restrict__ Wp,
                               const float* __restrict__ Wk,
                               const float* __restrict__ Wv,
                               ushort* __restrict__ xb,
                               ushort* __restrict__ Wqb,
                               ushort* __restrict__ Wpb,
                               ushort* __restrict__ Wkvb) {
    const int S0 = M_N * C_N / 4;
    const int S1 = S0 + C_N * C_N / 4;
    const int S2 = S1 + C_N * C_N / 4;
    const int S3 = S2 + HS_N * C_N / 4;
    const int S4 = S3 + HS_N * C_N / 4;
    const int stride = gridDim.x * blockDim.x;
    for (int i = blockIdx.x * blockDim.x + threadIdx.x; i < S4; i += stride) {
        const float* src; ushort* dst; int j; float sc = 1.f;
        if (i < S0)      { src = x;  dst = xb;   j = i; }
        else if (i < S1) { src = Wq; dst = Wqb;  j = i - S0; sc = QSCALE; }
        else if (i < S2) { src = Wp; dst = Wpb;  j = i - S1; }
        else if (i < S3) { src = Wk; dst = Wkvb; j = i - S2; }
        else             { src = Wv; dst = Wkvb + HS_N * C_N; j = i - S3; }
        const float4 f = ((const float4*)src)[j];
        ushort4 o;
        o.x = f2bf(f.x * sc); o.y = f2bf(f.y * sc);
        o.z = f2bf(f.z * sc); o.w = f2bf(f.w * sc);
        ((ushort4*)dst)[j] = o;
    }
}

// ---------------------------------------------------------------------------
// bf16 MFMA GEMM — BM=64, BN=128, BK=64, 256 threads (4 waves 2x2, 32x64),
// 2-phase double-buffered k-loop (R8, kept: small positive). FROZEN.
// MODE 1 kv tile writes kb/vbt in MFMA FRAGMENT ORDER (see attn):
//   kfrag[key,d]  flat = ((((key>>4)*2+(d>>5))*4+((d>>3)&3))*16+(key&15))*8+(d&7)
//   vfrag[t,d]    flat = ((((t>>5)*4+(d>>4))*4+((t>>3)&3))*16+(d&15))*8+(t&7)
// ---------------------------------------------------------------------------
template <int MODE>
__global__ __launch_bounds__(256, 2) void gemm_bf16(
    const ushort* __restrict__ A,   // [M][K] bf16
    const ushort* __restrict__ W,   // [Ntot][K] bf16
    const float* __restrict__ bias, // MODE 0 only
    void* __restrict__ Cout,        // [M][1024] fp32 (MODE 0) / bf16 (MODE 1)
    ushort* __restrict__ kb,        // MODE 1: kfrag order, 4096*64
    ushort* __restrict__ vbt,       // MODE 1: vfrag order, 2*64*2048
    int K)                          // must be a multiple of 128 (nk even)
{
    __shared__ __align__(16) ushort As0[64 * 64];    // 8 KB
    __shared__ __align__(16) ushort Bs0[128 * 64];   // 16 KB
    __shared__ __align__(16) ushort As1[64 * 64];    // 8 KB
    __shared__ __align__(16) ushort Bs1[128 * 64];   // 16 KB
    // XCD swizzle (gridDim.x == 64 == M/64)
    const int flat = blockIdx.x + (blockIdx.y << 6);
    const int m0 = (((flat & 7) << 3) | ((flat >> 3) & 7)) * 64;
    const int n0 = (flat >> 6) * 128;
    const int tid = threadIdx.x;
    const int wid = tid >> 6;
    const int lane = tid & 63;
    const int ln = lane & 15;
    const int quad = lane >> 4;
    const int wm = wid >> 1, wn = wid & 1;   // wave = rows wm*32+, cols wn*64+

    f32x4 acc[2][4];
    #pragma unroll
    for (int i = 0; i < 2; ++i)
        #pragma unroll
        for (int j = 0; j < 4; ++j)
            acc[i][j] = (f32x4){0.f, 0.f, 0.f, 0.f};

    const int srow = lane >> 3;          // 0..7 row within 8-row segment
    const int schk = (lane & 7) ^ srow;  // fetched chunk (row&7 == srow)

    // issue the 6 async GLL16 loads for k-tile k0 into (Asb, Bsb)
    auto stage = [&](ushort* Asb, ushort* Bsb, int k0) {
        #pragma unroll
        for (int t = 0; t < 2; ++t) {    // A: 8 segments of 8 rows
            const int seg = wid * 2 + t;
            GLL16(A + (size_t)(m0 + seg * 8 + srow) * K + k0 + schk * 8,
                  Asb + seg * 512);
        }
        #pragma unroll
        for (int t = 0; t < 4; ++t) {    // B: 16 segments of 8 rows
            const int seg = wid * 4 + t;
            GLL16(W + (size_t)(n0 + seg * 8 + srow) * K + k0 + schk * 8,
                  Bsb + seg * 512);
        }
    };

    // consume one staged k-tile
    auto compute = [&](const ushort* Asb, const ushort* Bsb) {
        #pragma unroll
        for (int hh = 0; hh < 2; ++hh) {
            bf16x8 af[2], bf[4];
            const int sw = ln & 7;
            #pragma unroll
            for (int i = 0; i < 2; ++i) {
                const int row = wm * 32 + i * 16 + ln;
                af[i] = *(const bf16x8*)&Asb[row * 64 + (((hh * 4 + quad) ^ sw) * 8)];
            }
            #pragma unroll
            for (int j = 0; j < 4; ++j) {
                const int row = wn * 64 + j * 16 + ln;
                bf[j] = *(const bf16x8*)&Bsb[row * 64 + (((hh * 4 + quad) ^ sw) * 8)];
            }
            #pragma unroll
            for (int i = 0; i < 2; ++i)
                #pragma unroll
                for (int j = 0; j < 4; ++j)
                    acc[i][j] = __builtin_amdgcn_mfma_f32_16x16x32_bf16(
                        af[i], bf[j], acc[i][j], 0, 0, 0);
        }
    };

    const int nk = K >> 6;               // 16 for K=1024 (even)
    stage(As0, Bs0, 0);
    __syncthreads();                     // buf0 resident
    for (int kt = 0; kt < nk; kt += 2) {
        if (kt + 1 < nk) stage(As1, Bs1, (kt + 1) << 6);
        compute(As0, Bs0);
        __syncthreads();                 // buf1 loads (in flight during compute) done
        if (kt + 1 >= nk) break;
        if (kt + 2 < nk) stage(As0, Bs0, (kt + 2) << 6);
        compute(As1, Bs1);
        __syncthreads();                 // buf0 loads done
    }

    if (MODE == 1 && n0 >= C_N) {        // kv tile: K cols 0..63, V 64..127
        #pragma unroll
        for (int i = 0; i < 2; ++i) {
            const int row0 = m0 + wm * 32 + i * 16 + quad * 4;
            #pragma unroll
            for (int j = 0; j < 4; ++j) {
                const int c2 = wn * 64 + j * 16 + ln;
                if (c2 >= 64) {
                    // vfrag: 4 regs = t0..t0+3 (same 8-chunk since t0%4==0)
                    const int d = c2 - 64;
                    const int b = row0 >> 11;
                    const int t0 = row0 & 2047;
                    const int flatv = ((((t0 >> 5) * 4 + (d >> 4)) * 4
                                       + ((t0 >> 3) & 3)) * 16 + (d & 15)) * 8
                                      + (t0 & 7);
                    ushort4 pk;
                    pk.x = f2bf(acc[i][j][0]); pk.y = f2bf(acc[i][j][1]);
                    pk.z = f2bf(acc[i][j][2]); pk.w = f2bf(acc[i][j][3]);
                    *(ushort4*)&vbt[(size_t)b * HS_N * T_N + flatv] = pk;
                } else {
                    #pragma unroll
                    for (int reg = 0; reg < 4; ++reg) {
                        const int key = row0 + reg;   // global 0..4095
                        kb[((((key >> 4) * 2 + (c2 >> 5)) * 4
                             + ((c2 >> 3) & 3)) * 16 + (key & 15)) * 8
                           + (c2 & 7)] = f2bf(acc[i][j][reg]);
                    }
                }
            }
        }
        return;
    }

    #pragma unroll
    for (int i = 0; i < 2; ++i) {
        #pragma unroll
        for (int j = 0; j < 4; ++j) {
            const int col = n0 + wn * 64 + j * 16 + ln;
            const float bv = (MODE == 0) ? bias[col] : 0.f;
            #pragma unroll
            for (int reg = 0; reg < 4; ++reg) {
                const int row = m0 + wm * 32 + i * 16 + quad * 4 + reg;
                const float v = acc[i][j][reg] + bv;
                if (MODE == 0)
                    ((float*)Cout)[(size_t)row * C_N + col] = v;
                else
                    ((ushort*)Cout)[(size_t)row * C_N + col] = f2bf(v);
            }
        }
    }
}

// ---------------------------------------------------------------------------
// Flash causal MQA attention — KEY-SPLIT with PER-WAVE ASYNC LDS PIPELINE.
//
// R8 diagnosis: attn ~34us = ~1100 cyc serial/wave-tile; model says ~550
// VALU/trans + ~154 MFMA + ~400 EXPOSED L2 LOAD LATENCY. R7's register
// prefetch failed because +32 live VGPR blew the 256 budget (spills).
// Fix: prefetch through LDS (zero VGPR). kb/vbt are fragment-linear, so a
// wave's 8 fragments/tile are 8 contiguous 1KB blocks -> one GLL16 each
// (16B/lane) into a PER-WAVE private 8KB buffer (double-buffered, 64KB/
// block). Each wave reads only its own region -> NO barriers; the wave
// self-synchronizes with s_waitcnt vmcnt(8): after issuing tile kt+1's 8
// loads, the 8 newest outstanding are kt+1's, so vmcnt(8) (issue-order
// retirement) guarantees buf[kt] is resident. sched_barrier(0) fences
// (guide rule #18). Last tile: vmcnt(0). Post-loop vmcnt(0) drains the
// broken-wave path before Ored (36KB) overlays the buffers after the
// epilogue barrier. ds_read_b128 at lane*16 = conflict-free.
//
// Q uses the torch RAW-VIEW layout: Q[b,h,t,d] = qb[b*T*C + h*T*hs + t*hs + d].
// ---------------------------------------------------------------------------
__global__ __launch_bounds__(256, 2) void attn_mfma_kernel(
    const ushort* __restrict__ qb,
    const ushort* __restrict__ kb,    // kfrag order
    const ushort* __restrict__ vbt,   // vfrag order
    ushort* __restrict__ yb)
{
    __shared__ __align__(16) ushort smem[32768];   // 64 KB: 4 waves x 2 bufs x 8 KB

    const int bh = blockIdx.x;
    const int b = bh >> 4, h = bh & 15;
    const int yy = blockIdx.y;
    // balanced qt map: resident groups (yy, yy+8, yy+16, yy+24) have ~equal work
    const int qt = (yy < 8) ? 31 - yy : (yy < 16) ? yy - 8
                 : (yy < 24) ? 39 - yy : yy - 16;
    const int nkt = (qt >> 1) + 1;    // 128-key tiles
    const int qmax = qt * 64 + 63;

    const int tid = threadIdx.x;
    const int w = tid >> 6;           // wave id = key-slice owner
    const int lane = tid & 63;
    const int ln = lane & 15;
    const int quad = lane >> 4;

    // ---- Q fragments, held whole loop: qf[qb4][kc2], B-operand layout
    bf16x8 qf[4][2];
    {
        const ushort* qs_ = qb + (size_t)b * T_N * C_N
                          + (size_t)h * T_N * HS_N
                          + (size_t)(qt * 64) * HS_N;
        #pragma unroll
        for (int q4 = 0; q4 < 4; ++q4)
            #pragma unroll
            for (int kc = 0; kc < 2; ++kc)
                qf[q4][kc] = *(const bf16x8*)(qs_ + (q4 * 16 + ln) * HS_N
                                              + kc * 32 + quad * 8);
    }

    const ushort* vbb = vbt + (size_t)b * HS_N * T_N;
    ushort* mybuf = smem + w * 8192;       // this wave's 16 KB (2 bufs)

    // stage tile kt's 8 fragments (4 K + 4 V) into buf[kt&1] — async, per-wave
    auto stage = [&](int kt) {
        const int k0 = kt * 128;
        ushort* dst = mybuf + (kt & 1) * 4096;
        const int b16 = ((b * T_N + k0) >> 4) + w * 2;
        #pragma unroll
        for (int nt = 0; nt < 2; ++nt)
            #pragma unroll
            for (int kc = 0; kc < 2; ++kc)
                GLL16(kb + (size_t)((b16 + nt) * 2 + kc) * 512 + lane * 8,
                      dst + (nt * 2 + kc) * 512);
        const int t32 = (k0 >> 5) + w;
        #pragma unroll
        for (int db = 0; db < 4; ++db)
            GLL16(vbb + (size_t)(t32 * 4 + db) * 512 + lane * 8,
                  dst + (4 + db) * 512);
    };

    f32x4 o[4][4];                    // [db][qb]  o^T[d][q] partial (this wave's keys)
    #pragma unroll
    for (int i = 0; i < 4; ++i)
        #pragma unroll
        for (int j = 0; j < 4; ++j)
            o[i][j] = (f32x4){0.f, 0.f, 0.f, 0.f};
    float lac[4] = {0.f, 0.f, 0.f, 0.f};

    stage(0);

    for (int kt = 0; kt < nkt; ++kt) {
        const int k0 = kt * 128;
        const bool dg = (kt == nkt - 1);       // only last tile crosses the diagonal
        const int kw0 = k0 + w * 32;           // this wave's first key
        if (dg && kw0 > qmax) break;           // whole slice masked (drain after loop)

        if (kt + 1 < nkt) {
            stage(kt + 1);
            __builtin_amdgcn_sched_barrier(0);
            asm volatile("s_waitcnt vmcnt(8)" ::: "memory");   // buf[kt] resident
        } else {
            __builtin_amdgcn_sched_barrier(0);
            asm volatile("s_waitcnt vmcnt(0)" ::: "memory");
        }
        __builtin_amdgcn_sched_barrier(0);

        // fragment reads from own LDS buffer: lane-linear, conflict-free
        const ushort* src = mybuf + (kt & 1) * 4096;
        bf16x8 kf[2][2], vf[4];
        #pragma unroll
        for (int nt = 0; nt < 2; ++nt)
            #pragma unroll
            for (int kc = 0; kc < 2; ++kc)
                kf[nt][kc] = *(const bf16x8*)&src[(nt * 2 + kc) * 512 + lane * 8];
        #pragma unroll
        for (int db = 0; db < 4; ++db)
            vf[db] = *(const bf16x8*)&src[(4 + db) * 512 + lane * 8];

        // QK^T: sc[nt][qb] = S^T[key = kw0+nt*16+quad*4+reg][q = qt*64+q4*16+ln]
        f32x4 sc[2][4];
        #pragma unroll
        for (int nt = 0; nt < 2; ++nt)
            #pragma unroll
            for (int q4 = 0; q4 < 4; ++q4) {
                f32x4 s = (f32x4){0.f, 0.f, 0.f, 0.f};
                s = __builtin_amdgcn_mfma_f32_16x16x32_bf16(kf[nt][0], qf[q4][0], s, 0, 0, 0);
                s = __builtin_amdgcn_mfma_f32_16x16x32_bf16(kf[nt][1], qf[q4][1], s, 0, 0, 0);
                sc[nt][q4] = s;
            }

        // softmax + pack:  pk[nt][q4][hf] = bf16 pair for keys (quad*4+2hf, +1)
        unsigned pk[2][4][2];
        #pragma unroll
        for (int nt = 0; nt < 2; ++nt)
            #pragma unroll
            for (int q4 = 0; q4 < 4; ++q4) {
                f32x4 s = sc[nt][q4];
                if (dg) {
                    const int qg = qt * 64 + q4 * 16 + ln;
                    #pragma unroll
                    for (int reg = 0; reg < 4; ++reg) {
                        const int key = kw0 + nt * 16 + quad * 4 + reg;
                        if (key > qg) s[reg] = -1e30f;
                    }
                }
                const float p0 = __builtin_amdgcn_exp2f(s[0]);
                const float p1 = __builtin_amdgcn_exp2f(s[1]);
                const float p2 = __builtin_amdgcn_exp2f(s[2]);
                const float p3 = __builtin_amdgcn_exp2f(s[3]);
                lac[q4] += (p0 + p1) + (p2 + p3);
                pk[nt][q4][0] = pack2_trunc(p0, p1);
                pk[nt][q4][1] = pack2_trunc(p2, p3);
            }

        // in-register transpose (D-layout -> B-operand) + PV
        #pragma unroll
        for (int q4 = 0; q4 < 4; ++q4) {
            u32x2 ab0 = __builtin_amdgcn_permlane32_swap(pk[0][q4][0], pk[1][q4][0], false, false);
            u32x2 rs0 = __builtin_amdgcn_permlane16_swap(ab0[0], ab0[1], false, false);
            u32x2 ab1 = __builtin_amdgcn_permlane32_swap(pk[0][q4][1], pk[1][q4][1], false, false);
            u32x2 rs1 = __builtin_amdgcn_permlane16_swap(ab1[0], ab1[1], false, false);
            u32x4 pw;
            pw[0] = rs0[0]; pw[1] = rs1[0]; pw[2] = rs0[1]; pw[3] = rs1[1];
            const bf16x8 pf = __builtin_bit_cast(bf16x8, pw);
            #pragma unroll
            for (int db = 0; db < 4; ++db)
                o[db][q4] = __builtin_amdgcn_mfma_f32_16x16x32_bf16(
                    vf[db], pf, o[db][q4], 0, 0, 0);
        }
    }

    // drain any in-flight prefetch (broken-wave path) before LDS reuse
    asm volatile("s_waitcnt vmcnt(0)" ::: "memory");

    // ---- epilogue: cross-wave reduce o^T and l, normalize, write y (bf16)
    // per-wave l: reduce over quads first (each lane then holds l[q=q4*16+ln])
    #pragma unroll
    for (int q4 = 0; q4 < 4; ++q4) {
        lac[q4] += __shfl_xor(lac[q4], 16);
        lac[q4] += __shfl_xor(lac[q4], 32);
    }

    float* Ored = (float*)smem;            // 36 KB overlay, safe after barrier
    const int qloc = 16 * w + (lane >> 2); // q-row this lane reduces
    float inv = 0.f;

    #pragma unroll
    for (int pass = 0; pass < 2; ++pass) { // d 0..31 then 32..63
        __syncthreads();                   // all waves' loops done / pass0 reads done
        #pragma unroll
        for (int db2 = 0; db2 < 2; ++db2)
            #pragma unroll
            for (int q4 = 0; q4 < 4; ++q4)
                *(f32x4*)&Ored[(w * 64 + q4 * 16 + ln) * 36 + db2 * 16 + quad * 4]
                    = o[pass * 2 + db2][q4];
        if (pass == 0 && quad == 0) {
            #pragma unroll
            for (int q4 = 0; q4 < 4; ++q4)
                Ored[(w * 64 + q4 * 16 + ln) * 36 + 32] = lac[q4];
        }
        __syncthreads();

        f32x4 a0 = (f32x4){0.f, 0.f, 0.f, 0.f};
        f32x4 a1 = (f32x4){0.f, 0.f, 0.f, 0.f};
        float ls = 0.f;
        #pragma unroll
        for (int v = 0; v < 4; ++v) {
            const int base = (v * 64 + qloc) * 36;
            a0 += *(const f32x4*)&Ored[base + (lane & 3) * 4];
            a1 += *(const f32x4*)&Ored[base + 16 + (lane & 3) * 4];
            if (pass == 0) ls += Ored[base + 32];
        }
        if (pass == 0) inv = 1.0f / ls;

        const int qg = qt * 64 + qloc;
        ushort* yrow = yb + ((size_t)b * T_N + qg) * C_N + h * HS_N
                       + pass * 32 + (lane & 3) * 4;
        ushort4 s0, s1;
        s0.x = f2bf(a0[0] * inv); s0.y = f2bf(a0[1] * inv);
        s0.z = f2bf(a0[2] * inv); s0.w = f2bf(a0[3] * inv);
        s1.x = f2bf(a1[0] * inv); s1.y = f2bf(a1[1] * inv);
        s1.z = f2bf(a1[2] * inv); s1.w = f2bf(a1[3] * inv);
        *(ushort4*)yrow = s0;
        *(ushort4*)(yrow + 16) = s1;
    }
}

// ---------------------------------------------------------------------------
extern "C" void kernel_launch(void* const* d_in, const int* in_sizes, int n_in,
                              void* d_out, int out_size, void* d_ws, size_t ws_size,
                              hipStream_t stream) {
    const float* x  = (const float*)d_in[0];
    const float* Wk = (const float*)d_in[1];
    const float* Wv = (const float*)d_in[2];
    const float* Wq = (const float*)d_in[3];
    const float* Wp = (const float*)d_in[4];
    const float* bp = (const float*)d_in[5];
    float* out = (float*)d_out;

    ushort* xb   = (ushort*)d_ws;                     // [4096][1024]
    ushort* qb   = xb   + (size_t)M_N * C_N;          // [4096][1024]
    ushort* yb   = qb   + (size_t)M_N * C_N;          // [4096][1024]
    ushort* kbw  = yb   + (size_t)M_N * C_N;          // kfrag, 4096*64
    ushort* vbt  = kbw  + (size_t)M_N * HS_N;         // vfrag, 2*64*2048
    ushort* Wqb  = vbt  + (size_t)B_N * HS_N * T_N;   // [1024][1024] (scaled)
    ushort* Wkvb = Wqb  + (size_t)C_N * C_N;          // [128][1024], after Wq
    ushort* Wpb  = Wkvb + (size_t)128 * C_N;          // [1024][1024]

    cvt_all_kernel<<<1024, 256, 0, stream>>>(x, Wq, Wp, Wk, Wv,
                                             xb, Wqb, Wpb, Wkvb);

    // fused q + k + v projection: W' = [Wq(scaled); Wk; Wv] (1152 rows)
    // n-tiles 0..7 -> qb; tile 8 -> kbw + vbt in fragment order
    gemm_bf16<1><<<dim3(M_N / 64, (C_N + 128) / 128), 256, 0, stream>>>(
        xb, Wqb, nullptr, qb, kbw, vbt, C_N);

    // attention -> yb bf16; key-split, per-wave async LDS pipeline
    attn_mfma_kernel<<<dim3(B_N * H_N, 32), 256, 0, stream>>>(qb, kbw, vbt, yb);

    // out = y @ Wp^T + bp -> fp32
    gemm_bf16<0><<<dim3(M_N / 64, C_N / 128), 256, 0, stream>>>(
        yb, Wpb, bp, out, nullptr, nullptr, C_N);
}

// Round 10
// 141.308 us; speedup vs baseline: 1.0248x; 1.0248x over previous
//
#include <hip/hip_runtime.h>
#include <cstddef>
#include <cstdint>

// Problem constants: B=2, T=2048, C=1024, H=16, hs=64
#define B_N 2
#define T_N 2048
#define C_N 1024
#define H_N 16
#define HS_N 64
#define M_N (B_N * T_N)   // 4096

typedef __attribute__((ext_vector_type(8))) short bf16x8;   // 8 bf16 = 4 VGPRs
typedef __attribute__((ext_vector_type(4))) float f32x4;
typedef __attribute__((ext_vector_type(4))) unsigned int u32x4;
typedef __attribute__((ext_vector_type(2))) unsigned int u32x2;

// 0.125 (hs^-0.5) * log2(e): folded into Wq so attention uses exp2 directly
#define QSCALE 0.18033688011112042f

__device__ __forceinline__ ushort f2bf(float f) {
    union { float f; uint32_t u; } v; v.f = f;
    uint32_t r = v.u + 0x7fffu + ((v.u >> 16) & 1u);   // round-nearest-even
    return (ushort)(r >> 16);
}
// truncating pack of two P-values (P in [0,1], rel err ~2^-9 — validated)
__device__ __forceinline__ unsigned pack2_trunc(float a, float b) {
    union { float f; uint32_t u; } x, y; x.f = a; y.f = b;
    return (x.u >> 16) | (y.u & 0xFFFF0000u);
}

// async global->LDS, 16B per lane; lds base must be wave-uniform
#define GLL16(g, l)                                                         \
    __builtin_amdgcn_global_load_lds(                                       \
        (const __attribute__((address_space(1))) unsigned int*)(g),         \
        (__attribute__((address_space(3))) unsigned int*)(l), 16, 0, 0)

// ---------------------------------------------------------------------------
// Fused fp32->bf16 convert: x | Wq(*QSCALE) | Wp | Wk | Wv (one launch).
// ---------------------------------------------------------------------------
__global__ void cvt_all_kernel(const float* __restrict__ x,
                               const float* __restrict__ Wq,
                               const float* __restrict__ Wp,
                               const float* __restrict__ Wk,
                               const float* __restrict__ Wv,
                               ushort* __restrict__ xb,
                               ushort* __restrict__ Wqb,
                               ushort* __restrict__ Wpb,
                               ushort* __restrict__ Wkvb) {
    const int S0 = M_N * C_N / 4;
    const int S1 = S0 + C_N * C_N / 4;
    const int S2 = S1 + C_N * C_N / 4;
    const int S3 = S2 + HS_N * C_N / 4;
    const int S4 = S3 + HS_N * C_N / 4;
    const int stride = gridDim.x * blockDim.x;
    for (int i = blockIdx.x * blockDim.x + threadIdx.x; i < S4; i += stride) {
        const float* src; ushort* dst; int j; float sc = 1.f;
        if (i < S0)      { src = x;  dst = xb;   j = i; }
        else if (i < S1) { src = Wq; dst = Wqb;  j = i - S0; sc = QSCALE; }
        else if (i < S2) { src = Wp; dst = Wpb;  j = i - S1; }
        else if (i < S3) { src = Wk; dst = Wkvb; j = i - S2; }
        else             { src = Wv; dst = Wkvb + HS_N * C_N; j = i - S3; }
        const float4 f = ((const float4*)src)[j];
        ushort4 o;
        o.x = f2bf(f.x * sc); o.y = f2bf(f.y * sc);
        o.z = f2bf(f.z * sc); o.w = f2bf(f.w * sc);
        ((ushort4*)dst)[j] = o;
    }
}

// ---------------------------------------------------------------------------
// bf16 MFMA GEMM — BM=64, BN=128, BK=64, 256 threads (4 waves 2x2, 32x64),
// 2-phase double-buffered k-loop (R8).
// NEW this round: __launch_bounds__(256,3) -> 3 blocks/CU (LDS 48KB x 3 =
// 144KB <= 160KB; VGPR ~110 <= 170 cap). Removes gemm1's 64-block straggler
// tail (576 blocks vs 512 resident at 2/CU) and adds 12 waves/CU of overlap
// to hide the per-k-step barrier drain.
// MODE 1 kv tile writes kb/vbt in MFMA FRAGMENT ORDER (see attn):
//   kfrag[key,d]  flat = ((((key>>4)*2+(d>>5))*4+((d>>3)&3))*16+(key&15))*8+(d&7)
//   vfrag[t,d]    flat = ((((t>>5)*4+(d>>4))*4+((t>>3)&3))*16+(d&15))*8+(t&7)
// ---------------------------------------------------------------------------
template <int MODE>
__global__ __launch_bounds__(256, 3) void gemm_bf16(
    const ushort* __restrict__ A,   // [M][K] bf16
    const ushort* __restrict__ W,   // [Ntot][K] bf16
    const float* __restrict__ bias, // MODE 0 only
    void* __restrict__ Cout,        // [M][1024] fp32 (MODE 0) / bf16 (MODE 1)
    ushort* __restrict__ kb,        // MODE 1: kfrag order, 4096*64
    ushort* __restrict__ vbt,       // MODE 1: vfrag order, 2*64*2048
    int K)                          // must be a multiple of 128 (nk even)
{
    __shared__ __align__(16) ushort As0[64 * 64];    // 8 KB
    __shared__ __align__(16) ushort Bs0[128 * 64];   // 16 KB
    __shared__ __align__(16) ushort As1[64 * 64];    // 8 KB
    __shared__ __align__(16) ushort Bs1[128 * 64];   // 16 KB
    // XCD swizzle (gridDim.x == 64 == M/64)
    const int flat = blockIdx.x + (blockIdx.y << 6);
    const int m0 = (((flat & 7) << 3) | ((flat >> 3) & 7)) * 64;
    const int n0 = (flat >> 6) * 128;
    const int tid = threadIdx.x;
    const int wid = tid >> 6;
    const int lane = tid & 63;
    const int ln = lane & 15;
    const int quad = lane >> 4;
    const int wm = wid >> 1, wn = wid & 1;   // wave = rows wm*32+, cols wn*64+

    f32x4 acc[2][4];
    #pragma unroll
    for (int i = 0; i < 2; ++i)
        #pragma unroll
        for (int j = 0; j < 4; ++j)
            acc[i][j] = (f32x4){0.f, 0.f, 0.f, 0.f};

    const int srow = lane >> 3;          // 0..7 row within 8-row segment
    const int schk = (lane & 7) ^ srow;  // fetched chunk (row&7 == srow)

    // issue the 6 async GLL16 loads for k-tile k0 into (Asb, Bsb)
    auto stage = [&](ushort* Asb, ushort* Bsb, int k0) {
        #pragma unroll
        for (int t = 0; t < 2; ++t) {    // A: 8 segments of 8 rows
            const int seg = wid * 2 + t;
            GLL16(A + (size_t)(m0 + seg * 8 + srow) * K + k0 + schk * 8,
                  Asb + seg * 512);
        }
        #pragma unroll
        for (int t = 0; t < 4; ++t) {    // B: 16 segments of 8 rows
            const int seg = wid * 4 + t;
            GLL16(W + (size_t)(n0 + seg * 8 + srow) * K + k0 + schk * 8,
                  Bsb + seg * 512);
        }
    };

    // consume one staged k-tile
    auto compute = [&](const ushort* Asb, const ushort* Bsb) {
        #pragma unroll
        for (int hh = 0; hh < 2; ++hh) {
            bf16x8 af[2], bf[4];
            const int sw = ln & 7;
            #pragma unroll
            for (int i = 0; i < 2; ++i) {
                const int row = wm * 32 + i * 16 + ln;
                af[i] = *(const bf16x8*)&Asb[row * 64 + (((hh * 4 + quad) ^ sw) * 8)];
            }
            #pragma unroll
            for (int j = 0; j < 4; ++j) {
                const int row = wn * 64 + j * 16 + ln;
                bf[j] = *(const bf16x8*)&Bsb[row * 64 + (((hh * 4 + quad) ^ sw) * 8)];
            }
            #pragma unroll
            for (int i = 0; i < 2; ++i)
                #pragma unroll
                for (int j = 0; j < 4; ++j)
                    acc[i][j] = __builtin_amdgcn_mfma_f32_16x16x32_bf16(
                        af[i], bf[j], acc[i][j], 0, 0, 0);
        }
    };

    const int nk = K >> 6;               // 16 for K=1024 (even)
    stage(As0, Bs0, 0);
    __syncthreads();                     // buf0 resident
    for (int kt = 0; kt < nk; kt += 2) {
        if (kt + 1 < nk) stage(As1, Bs1, (kt + 1) << 6);
        compute(As0, Bs0);
        __syncthreads();                 // buf1 loads (in flight during compute) done
        if (kt + 1 >= nk) break;
        if (kt + 2 < nk) stage(As0, Bs0, (kt + 2) << 6);
        compute(As1, Bs1);
        __syncthreads();                 // buf0 loads done
    }

    if (MODE == 1 && n0 >= C_N) {        // kv tile: K cols 0..63, V 64..127
        #pragma unroll
        for (int i = 0; i < 2; ++i) {
            const int row0 = m0 + wm * 32 + i * 16 + quad * 4;
            #pragma unroll
            for (int j = 0; j < 4; ++j) {
                const int c2 = wn * 64 + j * 16 + ln;
                if (c2 >= 64) {
                    // vfrag: 4 regs = t0..t0+3 (same 8-chunk since t0%4==0)
                    const int d = c2 - 64;
                    const int b = row0 >> 11;
                    const int t0 = row0 & 2047;
                    const int flatv = ((((t0 >> 5) * 4 + (d >> 4)) * 4
                                       + ((t0 >> 3) & 3)) * 16 + (d & 15)) * 8
                                      + (t0 & 7);
                    ushort4 pk;
                    pk.x = f2bf(acc[i][j][0]); pk.y = f2bf(acc[i][j][1]);
                    pk.z = f2bf(acc[i][j][2]); pk.w = f2bf(acc[i][j][3]);
                    *(ushort4*)&vbt[(size_t)b * HS_N * T_N + flatv] = pk;
                } else {
                    #pragma unroll
                    for (int reg = 0; reg < 4; ++reg) {
                        const int key = row0 + reg;   // global 0..4095
                        kb[((((key >> 4) * 2 + (c2 >> 5)) * 4
                             + ((c2 >> 3) & 3)) * 16 + (key & 15)) * 8
                           + (c2 & 7)] = f2bf(acc[i][j][reg]);
                    }
                }
            }
        }
        return;
    }

    #pragma unroll
    for (int i = 0; i < 2; ++i) {
        #pragma unroll
        for (int j = 0; j < 4; ++j) {
            const int col = n0 + wn * 64 + j * 16 + ln;
            const float bv = (MODE == 0) ? bias[col] : 0.f;
            #pragma unroll
            for (int reg = 0; reg < 4; ++reg) {
                const int row = m0 + wm * 32 + i * 16 + quad * 4 + reg;
                const float v = acc[i][j][reg] + bv;
                if (MODE == 0)
                    ((float*)Cout)[(size_t)row * C_N + col] = v;
                else
                    ((ushort*)Cout)[(size_t)row * C_N + col] = f2bf(v);
            }
        }
    }
}

// ---------------------------------------------------------------------------
// Flash causal MQA attention — KEY-SPLIT, ZERO-STAGING (R8 form, reverted
// from R9's per-wave LDS pipeline: −3.2us; second null on the load-latency
// theory. With 2 waves/SIMD the other wave's ~700cyc compute already covers
// a wave's ~400cyc L2 wait — latency was never exposed).
//
// K/V pre-swizzled into MFMA fragment order by gemm1 (coalesced 16B/lane
// L2 streams); no barriers, no LDS in the k-loop. LDS = 36KB epilogue only.
// Q uses the torch RAW-VIEW layout: Q[b,h,t,d] = qb[b*T*C + h*T*hs + t*hs + d].
// ---------------------------------------------------------------------------
__global__ __launch_bounds__(256, 2) void attn_mfma_kernel(
    const ushort* __restrict__ qb,
    const ushort* __restrict__ kb,    // kfrag order
    const ushort* __restrict__ vbt,   // vfrag order
    ushort* __restrict__ yb)
{
    __shared__ __align__(16) float Ored[4 * 64 * 36];   // 36 KB epilogue only

    const int bh = blockIdx.x;
    const int b = bh >> 4, h = bh & 15;
    const int yy = blockIdx.y;
    // balanced qt map: resident groups (yy, yy+8, yy+16, yy+24) have ~equal work
    const int qt = (yy < 8) ? 31 - yy : (yy < 16) ? yy - 8
                 : (yy < 24) ? 39 - yy : yy - 16;
    const int nkt = (qt >> 1) + 1;    // 128-key tiles
    const int qmax = qt * 64 + 63;

    const int tid = threadIdx.x;
    const int w = tid >> 6;           // wave id = key-slice owner
    const int lane = tid & 63;
    const int ln = lane & 15;
    const int quad = lane >> 4;

    // ---- Q fragments, held whole loop: qf[qb4][kc2], B-operand layout
    bf16x8 qf[4][2];
    {
        const ushort* qs_ = qb + (size_t)b * T_N * C_N
                          + (size_t)h * T_N * HS_N
                          + (size_t)(qt * 64) * HS_N;
        #pragma unroll
        for (int q4 = 0; q4 < 4; ++q4)
            #pragma unroll
            for (int kc = 0; kc < 2; ++kc)
                qf[q4][kc] = *(const bf16x8*)(qs_ + (q4 * 16 + ln) * HS_N
                                              + kc * 32 + quad * 8);
    }

    const ushort* vbb = vbt + (size_t)b * HS_N * T_N;

    f32x4 o[4][4];                    // [db][qb]  o^T[d][q] partial (this wave's keys)
    #pragma unroll
    for (int i = 0; i < 4; ++i)
        #pragma unroll
        for (int j = 0; j < 4; ++j)
            o[i][j] = (f32x4){0.f, 0.f, 0.f, 0.f};
    float lac[4] = {0.f, 0.f, 0.f, 0.f};

    for (int kt = 0; kt < nkt; ++kt) {
        const int k0 = kt * 128;
        const bool dg = (kt == nkt - 1);       // only last tile crosses the diagonal
        const int kw0 = k0 + w * 32;           // this wave's first key
        if (dg && kw0 > qmax) break;           // whole slice masked; last tile anyway

        // fragment loads: coalesced 16B/lane, L2-resident
        const int b16 = ((b * T_N + k0) >> 4) + w * 2;   // key16 for nt=0
        bf16x8 kf[2][2], vf[4];
        #pragma unroll
        for (int nt = 0; nt < 2; ++nt)
            #pragma unroll
            for (int kc = 0; kc < 2; ++kc)
                kf[nt][kc] = *(const bf16x8*)
                    &kb[((((b16 + nt) * 2 + kc) * 4 + quad) * 16 + ln) * 8];
        const int t32 = (k0 >> 5) + w;
        #pragma unroll
        for (int db = 0; db < 4; ++db)
            vf[db] = *(const bf16x8*)
                &vbb[(((t32 * 4 + db) * 4 + quad) * 16 + ln) * 8];

        // QK^T: sc[nt][qb] = S^T[key = kw0+nt*16+quad*4+reg][q = qt*64+q4*16+ln]
        f32x4 sc[2][4];
        #pragma unroll
        for (int nt = 0; nt < 2; ++nt)
            #pragma unroll
            for (int q4 = 0; q4 < 4; ++q4) {
                f32x4 s = (f32x4){0.f, 0.f, 0.f, 0.f};
                s = __builtin_amdgcn_mfma_f32_16x16x32_bf16(kf[nt][0], qf[q4][0], s, 0, 0, 0);
                s = __builtin_amdgcn_mfma_f32_16x16x32_bf16(kf[nt][1], qf[q4][1], s, 0, 0, 0);
                sc[nt][q4] = s;
            }

        // softmax + pack:  pk[nt][q4][hf] = bf16 pair for keys (quad*4+2hf, +1)
        unsigned pk[2][4][2];
        #pragma unroll
        for (int nt = 0; nt < 2; ++nt)
            #pragma unroll
            for (int q4 = 0; q4 < 4; ++q4) {
                f32x4 s = sc[nt][q4];
                if (dg) {
                    const int qg = qt * 64 + q4 * 16 + ln;
                    #pragma unroll
                    for (int reg = 0; reg < 4; ++reg) {
                        const int key = kw0 + nt * 16 + quad * 4 + reg;
                        if (key > qg) s[reg] = -1e30f;
                    }
                }
                const float p0 = __builtin_amdgcn_exp2f(s[0]);
                const float p1 = __builtin_amdgcn_exp2f(s[1]);
                const float p2 = __builtin_amdgcn_exp2f(s[2]);
                const float p3 = __builtin_amdgcn_exp2f(s[3]);
                lac[q4] += (p0 + p1) + (p2 + p3);
                pk[nt][q4][0] = pack2_trunc(p0, p1);
                pk[nt][q4][1] = pack2_trunc(p2, p3);
            }

        // in-register transpose (D-layout -> B-operand) + PV
        #pragma unroll
        for (int q4 = 0; q4 < 4; ++q4) {
            u32x2 ab0 = __builtin_amdgcn_permlane32_swap(pk[0][q4][0], pk[1][q4][0], false, false);
            u32x2 rs0 = __builtin_amdgcn_permlane16_swap(ab0[0], ab0[1], false, false);
            u32x2 ab1 = __builtin_amdgcn_permlane32_swap(pk[0][q4][1], pk[1][q4][1], false, false);
            u32x2 rs1 = __builtin_amdgcn_permlane16_swap(ab1[0], ab1[1], false, false);
            u32x4 pw;
            pw[0] = rs0[0]; pw[1] = rs1[0]; pw[2] = rs0[1]; pw[3] = rs1[1];
            const bf16x8 pf = __builtin_bit_cast(bf16x8, pw);
            #pragma unroll
            for (int db = 0; db < 4; ++db)
                o[db][q4] = __builtin_amdgcn_mfma_f32_16x16x32_bf16(
                    vf[db], pf, o[db][q4], 0, 0, 0);
        }
    }

    // ---- epilogue: cross-wave reduce o^T and l, normalize, write y (bf16)
    // per-wave l: reduce over quads first (each lane then holds l[q=q4*16+ln])
    #pragma unroll
    for (int q4 = 0; q4 < 4; ++q4) {
        lac[q4] += __shfl_xor(lac[q4], 16);
        lac[q4] += __shfl_xor(lac[q4], 32);
    }

    const int qloc = 16 * w + (lane >> 2); // q-row this lane reduces
    float inv = 0.f;

    #pragma unroll
    for (int pass = 0; pass < 2; ++pass) { // d 0..31 then 32..63
        __syncthreads();                   // pass0 reads done (pass1) / entry
        #pragma unroll
        for (int db2 = 0; db2 < 2; ++db2)
            #pragma unroll
            for (int q4 = 0; q4 < 4; ++q4)
                *(f32x4*)&Ored[(w * 64 + q4 * 16 + ln) * 36 + db2 * 16 + quad * 4]
                    = o[pass * 2 + db2][q4];
        if (pass == 0 && quad == 0) {
            #pragma unroll
            for (int q4 = 0; q4 < 4; ++q4)
                Ored[(w * 64 + q4 * 16 + ln) * 36 + 32] = lac[q4];
        }
        __syncthreads();

        f32x4 a0 = (f32x4){0.f, 0.f, 0.f, 0.f};
        f32x4 a1 = (f32x4){0.f, 0.f, 0.f, 0.f};
        float ls = 0.f;
        #pragma unroll
        for (int v = 0; v < 4; ++v) {
            const int base = (v * 64 + qloc) * 36;
            a0 += *(const f32x4*)&Ored[base + (lane & 3) * 4];
            a1 += *(const f32x4*)&Ored[base + 16 + (lane & 3) * 4];
            if (pass == 0) ls += Ored[base + 32];
        }
        if (pass == 0) inv = 1.0f / ls;

        const int qg = qt * 64 + qloc;
        ushort* yrow = yb + ((size_t)b * T_N + qg) * C_N + h * HS_N
                       + pass * 32 + (lane & 3) * 4;
        ushort4 s0, s1;
        s0.x = f2bf(a0[0] * inv); s0.y = f2bf(a0[1] * inv);
        s0.z = f2bf(a0[2] * inv); s0.w = f2bf(a0[3] * inv);
        s1.x = f2bf(a1[0] * inv); s1.y = f2bf(a1[1] * inv);
        s1.z = f2bf(a1[2] * inv); s1.w = f2bf(a1[3] * inv);
        *(ushort4*)yrow = s0;
        *(ushort4*)(yrow + 16) = s1;
    }
}

// ---------------------------------------------------------------------------
extern "C" void kernel_launch(void* const* d_in, const int* in_sizes, int n_in,
                              void* d_out, int out_size, void* d_ws, size_t ws_size,
                              hipStream_t stream) {
    const float* x  = (const float*)d_in[0];
    const float* Wk = (const float*)d_in[1];
    const float* Wv = (const float*)d_in[2];
    const float* Wq = (const float*)d_in[3];
    const float* Wp = (const float*)d_in[4];
    const float* bp = (const float*)d_in[5];
    float* out = (float*)d_out;

    ushort* xb   = (ushort*)d_ws;                     // [4096][1024]
    ushort* qb   = xb   + (size_t)M_N * C_N;          // [4096][1024]
    ushort* yb   = qb   + (size_t)M_N * C_N;          // [4096][1024]
    ushort* kbw  = yb   + (size_t)M_N * C_N;          // kfrag, 4096*64
    ushort* vbt  = kbw  + (size_t)M_N * HS_N;         // vfrag, 2*64*2048
    ushort* Wqb  = vbt  + (size_t)B_N * HS_N * T_N;   // [1024][1024] (scaled)
    ushort* Wkvb = Wqb  + (size_t)C_N * C_N;          // [128][1024], after Wq
    ushort* Wpb  = Wkvb + (size_t)128 * C_N;          // [1024][1024]

    cvt_all_kernel<<<1024, 256, 0, stream>>>(x, Wq, Wp, Wk, Wv,
                                             xb, Wqb, Wpb, Wkvb);

    // fused q + k + v projection: W' = [Wq(scaled); Wk; Wv] (1152 rows)
    // n-tiles 0..7 -> qb; tile 8 -> kbw + vbt in fragment order
    gemm_bf16<1><<<dim3(M_N / 64, (C_N + 128) / 128), 256, 0, stream>>>(
        xb, Wqb, nullptr, qb, kbw, vbt, C_N);

    // attention -> yb bf16; key-split, zero-staging, 1024 blocks
    attn_mfma_kernel<<<dim3(B_N * H_N, 32), 256, 0, stream>>>(qb, kbw, vbt, yb);

    // out = y @ Wp^T + bp -> fp32
    gemm_bf16<0><<<dim3(M_N / 64, C_N / 128), 256, 0, stream>>>(
        yb, Wpb, bp, out, nullptr, nullptr, C_N);
}

// Round 11
// 138.808 us; speedup vs baseline: 1.0433x; 1.0180x over previous
//
#include <hip/hip_runtime.h>
#include <cstddef>
#include <cstdint>

// Problem constants: B=2, T=2048, C=1024, H=16, hs=64
#define B_N 2
#define T_N 2048
#define C_N 1024
#define H_N 16
#define HS_N 64
#define M_N (B_N * T_N)   // 4096

typedef __attribute__((ext_vector_type(8))) short bf16x8;   // 8 bf16 = 4 VGPRs
typedef __attribute__((ext_vector_type(4))) float f32x4;
typedef __attribute__((ext_vector_type(4))) unsigned int u32x4;
typedef __attribute__((ext_vector_type(2))) unsigned int u32x2;

// 0.125 (hs^-0.5) * log2(e): folded into Wq so attention uses exp2 directly
#define QSCALE 0.18033688011112042f

__device__ __forceinline__ ushort f2bf(float f) {
    union { float f; uint32_t u; } v; v.f = f;
    uint32_t r = v.u + 0x7fffu + ((v.u >> 16) & 1u);   // round-nearest-even
    return (ushort)(r >> 16);
}
// truncating pack of two P-values (P in [0,1], rel err ~2^-9 — validated)
__device__ __forceinline__ unsigned pack2_trunc(float a, float b) {
    union { float f; uint32_t u; } x, y; x.f = a; y.f = b;
    return (x.u >> 16) | (y.u & 0xFFFF0000u);
}

// async global->LDS, 16B per lane; lds base must be wave-uniform
#define GLL16(g, l)                                                         \
    __builtin_amdgcn_global_load_lds(                                       \
        (const __attribute__((address_space(1))) unsigned int*)(g),         \
        (__attribute__((address_space(3))) unsigned int*)(l), 16, 0, 0)

// ---------------------------------------------------------------------------
// Fused fp32->bf16 convert: x | Wq(*QSCALE) | Wp | Wk | Wv (one launch).
// ---------------------------------------------------------------------------
__global__ void cvt_all_kernel(const float* __restrict__ x,
                               const float* __restrict__ Wq,
                               const float* __restrict__ Wp,
                               const float* __restrict__ Wk,
                               const float* __restrict__ Wv,
                               ushort* __restrict__ xb,
                               ushort* __restrict__ Wqb,
                               ushort* __restrict__ Wpb,
                               ushort* __restrict__ Wkvb) {
    const int S0 = M_N * C_N / 4;
    const int S1 = S0 + C_N * C_N / 4;
    const int S2 = S1 + C_N * C_N / 4;
    const int S3 = S2 + HS_N * C_N / 4;
    const int S4 = S3 + HS_N * C_N / 4;
    const int stride = gridDim.x * blockDim.x;
    for (int i = blockIdx.x * blockDim.x + threadIdx.x; i < S4; i += stride) {
        const float* src; ushort* dst; int j; float sc = 1.f;
        if (i < S0)      { src = x;  dst = xb;   j = i; }
        else if (i < S1) { src = Wq; dst = Wqb;  j = i - S0; sc = QSCALE; }
        else if (i < S2) { src = Wp; dst = Wpb;  j = i - S1; }
        else if (i < S3) { src = Wk; dst = Wkvb; j = i - S2; }
        else             { src = Wv; dst = Wkvb + HS_N * C_N; j = i - S3; }
        const float4 f = ((const float4*)src)[j];
        ushort4 o;
        o.x = f2bf(f.x * sc); o.y = f2bf(f.y * sc);
        o.z = f2bf(f.z * sc); o.w = f2bf(f.w * sc);
        ((ushort4*)dst)[j] = o;
    }
}

// ---------------------------------------------------------------------------
// bf16 MFMA GEMM — BM=64, BN=128, BK=64, 256 threads (4 waves 2x2, 32x64),
// 2-phase double-buffered k-loop (R8), __launch_bounds__(256,3) (R10).
// FROZEN at R10 state (best measured: 141.3us).
// MODE 1 kv tile writes kb/vbt in MFMA FRAGMENT ORDER (see attn):
//   kfrag[key,d]  flat = ((((key>>4)*2+(d>>5))*4+((d>>3)&3))*16+(key&15))*8+(d&7)
//   vfrag[t,d]    flat = ((((t>>5)*4+(d>>4))*4+((t>>3)&3))*16+(d&15))*8+(t&7)
// ---------------------------------------------------------------------------
template <int MODE>
__global__ __launch_bounds__(256, 3) void gemm_bf16(
    const ushort* __restrict__ A,   // [M][K] bf16
    const ushort* __restrict__ W,   // [Ntot][K] bf16
    const float* __restrict__ bias, // MODE 0 only
    void* __restrict__ Cout,        // [M][1024] fp32 (MODE 0) / bf16 (MODE 1)
    ushort* __restrict__ kb,        // MODE 1: kfrag order, 4096*64
    ushort* __restrict__ vbt,       // MODE 1: vfrag order, 2*64*2048
    int K)                          // must be a multiple of 128 (nk even)
{
    __shared__ __align__(16) ushort As0[64 * 64];    // 8 KB
    __shared__ __align__(16) ushort Bs0[128 * 64];   // 16 KB
    __shared__ __align__(16) ushort As1[64 * 64];    // 8 KB
    __shared__ __align__(16) ushort Bs1[128 * 64];   // 16 KB
    // XCD swizzle (gridDim.x == 64 == M/64)
    const int flat = blockIdx.x + (blockIdx.y << 6);
    const int m0 = (((flat & 7) << 3) | ((flat >> 3) & 7)) * 64;
    const int n0 = (flat >> 6) * 128;
    const int tid = threadIdx.x;
    const int wid = tid >> 6;
    const int lane = tid & 63;
    const int ln = lane & 15;
    const int quad = lane >> 4;
    const int wm = wid >> 1, wn = wid & 1;   // wave = rows wm*32+, cols wn*64+

    f32x4 acc[2][4];
    #pragma unroll
    for (int i = 0; i < 2; ++i)
        #pragma unroll
        for (int j = 0; j < 4; ++j)
            acc[i][j] = (f32x4){0.f, 0.f, 0.f, 0.f};

    const int srow = lane >> 3;          // 0..7 row within 8-row segment
    const int schk = (lane & 7) ^ srow;  // fetched chunk (row&7 == srow)

    // issue the 6 async GLL16 loads for k-tile k0 into (Asb, Bsb)
    auto stage = [&](ushort* Asb, ushort* Bsb, int k0) {
        #pragma unroll
        for (int t = 0; t < 2; ++t) {    // A: 8 segments of 8 rows
            const int seg = wid * 2 + t;
            GLL16(A + (size_t)(m0 + seg * 8 + srow) * K + k0 + schk * 8,
                  Asb + seg * 512);
        }
        #pragma unroll
        for (int t = 0; t < 4; ++t) {    // B: 16 segments of 8 rows
            const int seg = wid * 4 + t;
            GLL16(W + (size_t)(n0 + seg * 8 + srow) * K + k0 + schk * 8,
                  Bsb + seg * 512);
        }
    };

    // consume one staged k-tile
    auto compute = [&](const ushort* Asb, const ushort* Bsb) {
        #pragma unroll
        for (int hh = 0; hh < 2; ++hh) {
            bf16x8 af[2], bf[4];
            const int sw = ln & 7;
            #pragma unroll
            for (int i = 0; i < 2; ++i) {
                const int row = wm * 32 + i * 16 + ln;
                af[i] = *(const bf16x8*)&Asb[row * 64 + (((hh * 4 + quad) ^ sw) * 8)];
            }
            #pragma unroll
            for (int j = 0; j < 4; ++j) {
                const int row = wn * 64 + j * 16 + ln;
                bf[j] = *(const bf16x8*)&Bsb[row * 64 + (((hh * 4 + quad) ^ sw) * 8)];
            }
            #pragma unroll
            for (int i = 0; i < 2; ++i)
                #pragma unroll
                for (int j = 0; j < 4; ++j)
                    acc[i][j] = __builtin_amdgcn_mfma_f32_16x16x32_bf16(
                        af[i], bf[j], acc[i][j], 0, 0, 0);
        }
    };

    const int nk = K >> 6;               // 16 for K=1024 (even)
    stage(As0, Bs0, 0);
    __syncthreads();                     // buf0 resident
    for (int kt = 0; kt < nk; kt += 2) {
        if (kt + 1 < nk) stage(As1, Bs1, (kt + 1) << 6);
        compute(As0, Bs0);
        __syncthreads();                 // buf1 loads (in flight during compute) done
        if (kt + 1 >= nk) break;
        if (kt + 2 < nk) stage(As0, Bs0, (kt + 2) << 6);
        compute(As1, Bs1);
        __syncthreads();                 // buf0 loads done
    }

    if (MODE == 1 && n0 >= C_N) {        // kv tile: K cols 0..63, V 64..127
        #pragma unroll
        for (int i = 0; i < 2; ++i) {
            const int row0 = m0 + wm * 32 + i * 16 + quad * 4;
            #pragma unroll
            for (int j = 0; j < 4; ++j) {
                const int c2 = wn * 64 + j * 16 + ln;
                if (c2 >= 64) {
                    // vfrag: 4 regs = t0..t0+3 (same 8-chunk since t0%4==0)
                    const int d = c2 - 64;
                    const int b = row0 >> 11;
                    const int t0 = row0 & 2047;
                    const int flatv = ((((t0 >> 5) * 4 + (d >> 4)) * 4
                                       + ((t0 >> 3) & 3)) * 16 + (d & 15)) * 8
                                      + (t0 & 7);
                    ushort4 pk;
                    pk.x = f2bf(acc[i][j][0]); pk.y = f2bf(acc[i][j][1]);
                    pk.z = f2bf(acc[i][j][2]); pk.w = f2bf(acc[i][j][3]);
                    *(ushort4*)&vbt[(size_t)b * HS_N * T_N + flatv] = pk;
                } else {
                    #pragma unroll
                    for (int reg = 0; reg < 4; ++reg) {
                        const int key = row0 + reg;   // global 0..4095
                        kb[((((key >> 4) * 2 + (c2 >> 5)) * 4
                             + ((c2 >> 3) & 3)) * 16 + (key & 15)) * 8
                           + (c2 & 7)] = f2bf(acc[i][j][reg]);
                    }
                }
            }
        }
        return;
    }

    #pragma unroll
    for (int i = 0; i < 2; ++i) {
        #pragma unroll
        for (int j = 0; j < 4; ++j) {
            const int col = n0 + wn * 64 + j * 16 + ln;
            const float bv = (MODE == 0) ? bias[col] : 0.f;
            #pragma unroll
            for (int reg = 0; reg < 4; ++reg) {
                const int row = m0 + wm * 32 + i * 16 + quad * 4 + reg;
                const float v = acc[i][j][reg] + bv;
                if (MODE == 0)
                    ((float*)Cout)[(size_t)row * C_N + col] = v;
                else
                    ((ushort*)Cout)[(size_t)row * C_N + col] = f2bf(v);
            }
        }
    }
}

// ---------------------------------------------------------------------------
// Flash causal MQA attention — KEY-SPLIT, ZERO-STAGING (R8/R10 form).
// NEW this round: __launch_bounds__(256,3) — the ONLY untested occupancy
// axis. The k-loop is barrier-free, so latency hiding is pure TLP; R9's
// post-mortem showed the partner wave's compute is what covers the ~400cyc
// L2 wait. 2 -> 3 waves/SIMD = 1.5x coverage, zero structural change.
// LDS 36KB x 3 = 108 <= 160KB. VGPR must fit ~168 (was ~190 free-run):
// allocator remat is acceptable; spills would show as a regression.
//
// K/V pre-swizzled into MFMA fragment order by gemm1 (coalesced 16B/lane
// L2 streams); no barriers, no LDS in the k-loop. LDS = 36KB epilogue only.
// Q uses the torch RAW-VIEW layout: Q[b,h,t,d] = qb[b*T*C + h*T*hs + t*hs + d].
// ---------------------------------------------------------------------------
__global__ __launch_bounds__(256, 3) void attn_mfma_kernel(
    const ushort* __restrict__ qb,
    const ushort* __restrict__ kb,    // kfrag order
    const ushort* __restrict__ vbt,   // vfrag order
    ushort* __restrict__ yb)
{
    __shared__ __align__(16) float Ored[4 * 64 * 36];   // 36 KB epilogue only

    const int bh = blockIdx.x;
    const int b = bh >> 4, h = bh & 15;
    const int yy = blockIdx.y;
    // balanced qt map: resident groups (yy, yy+8, yy+16, yy+24) have ~equal work
    const int qt = (yy < 8) ? 31 - yy : (yy < 16) ? yy - 8
                 : (yy < 24) ? 39 - yy : yy - 16;
    const int nkt = (qt >> 1) + 1;    // 128-key tiles
    const int qmax = qt * 64 + 63;

    const int tid = threadIdx.x;
    const int w = tid >> 6;           // wave id = key-slice owner
    const int lane = tid & 63;
    const int ln = lane & 15;
    const int quad = lane >> 4;

    // ---- Q fragments, held whole loop: qf[qb4][kc2], B-operand layout
    bf16x8 qf[4][2];
    {
        const ushort* qs_ = qb + (size_t)b * T_N * C_N
                          + (size_t)h * T_N * HS_N
                          + (size_t)(qt * 64) * HS_N;
        #pragma unroll
        for (int q4 = 0; q4 < 4; ++q4)
            #pragma unroll
            for (int kc = 0; kc < 2; ++kc)
                qf[q4][kc] = *(const bf16x8*)(qs_ + (q4 * 16 + ln) * HS_N
                                              + kc * 32 + quad * 8);
    }

    const ushort* vbb = vbt + (size_t)b * HS_N * T_N;

    f32x4 o[4][4];                    // [db][qb]  o^T[d][q] partial (this wave's keys)
    #pragma unroll
    for (int i = 0; i < 4; ++i)
        #pragma unroll
        for (int j = 0; j < 4; ++j)
            o[i][j] = (f32x4){0.f, 0.f, 0.f, 0.f};
    float lac[4] = {0.f, 0.f, 0.f, 0.f};

    for (int kt = 0; kt < nkt; ++kt) {
        const int k0 = kt * 128;
        const bool dg = (kt == nkt - 1);       // only last tile crosses the diagonal
        const int kw0 = k0 + w * 32;           // this wave's first key
        if (dg && kw0 > qmax) break;           // whole slice masked; last tile anyway

        // fragment loads: coalesced 16B/lane, L2-resident
        const int b16 = ((b * T_N + k0) >> 4) + w * 2;   // key16 for nt=0
        bf16x8 kf[2][2], vf[4];
        #pragma unroll
        for (int nt = 0; nt < 2; ++nt)
            #pragma unroll
            for (int kc = 0; kc < 2; ++kc)
                kf[nt][kc] = *(const bf16x8*)
                    &kb[((((b16 + nt) * 2 + kc) * 4 + quad) * 16 + ln) * 8];
        const int t32 = (k0 >> 5) + w;
        #pragma unroll
        for (int db = 0; db < 4; ++db)
            vf[db] = *(const bf16x8*)
                &vbb[(((t32 * 4 + db) * 4 + quad) * 16 + ln) * 8];

        // QK^T: sc[nt][qb] = S^T[key = kw0+nt*16+quad*4+reg][q = qt*64+q4*16+ln]
        f32x4 sc[2][4];
        #pragma unroll
        for (int nt = 0; nt < 2; ++nt)
            #pragma unroll
            for (int q4 = 0; q4 < 4; ++q4) {
                f32x4 s = (f32x4){0.f, 0.f, 0.f, 0.f};
                s = __builtin_amdgcn_mfma_f32_16x16x32_bf16(kf[nt][0], qf[q4][0], s, 0, 0, 0);
                s = __builtin_amdgcn_mfma_f32_16x16x32_bf16(kf[nt][1], qf[q4][1], s, 0, 0, 0);
                sc[nt][q4] = s;
            }

        // softmax + pack:  pk[nt][q4][hf] = bf16 pair for keys (quad*4+2hf, +1)
        unsigned pk[2][4][2];
        #pragma unroll
        for (int nt = 0; nt < 2; ++nt)
            #pragma unroll
            for (int q4 = 0; q4 < 4; ++q4) {
                f32x4 s = sc[nt][q4];
                if (dg) {
                    const int qg = qt * 64 + q4 * 16 + ln;
                    #pragma unroll
                    for (int reg = 0; reg < 4; ++reg) {
                        const int key = kw0 + nt * 16 + quad * 4 + reg;
                        if (key > qg) s[reg] = -1e30f;
                    }
                }
                const float p0 = __builtin_amdgcn_exp2f(s[0]);
                const float p1 = __builtin_amdgcn_exp2f(s[1]);
                const float p2 = __builtin_amdgcn_exp2f(s[2]);
                const float p3 = __builtin_amdgcn_exp2f(s[3]);
                lac[q4] += (p0 + p1) + (p2 + p3);
                pk[nt][q4][0] = pack2_trunc(p0, p1);
                pk[nt][q4][1] = pack2_trunc(p2, p3);
            }

        // in-register transpose (D-layout -> B-operand) + PV
        #pragma unroll
        for (int q4 = 0; q4 < 4; ++q4) {
            u32x2 ab0 = __builtin_amdgcn_permlane32_swap(pk[0][q4][0], pk[1][q4][0], false, false);
            u32x2 rs0 = __builtin_amdgcn_permlane16_swap(ab0[0], ab0[1], false, false);
            u32x2 ab1 = __builtin_amdgcn_permlane32_swap(pk[0][q4][1], pk[1][q4][1], false, false);
            u32x2 rs1 = __builtin_amdgcn_permlane16_swap(ab1[0], ab1[1], false, false);
            u32x4 pw;
            pw[0] = rs0[0]; pw[1] = rs1[0]; pw[2] = rs0[1]; pw[3] = rs1[1];
            const bf16x8 pf = __builtin_bit_cast(bf16x8, pw);
            #pragma unroll
            for (int db = 0; db < 4; ++db)
                o[db][q4] = __builtin_amdgcn_mfma_f32_16x16x32_bf16(
                    vf[db], pf, o[db][q4], 0, 0, 0);
        }
    }

    // ---- epilogue: cross-wave reduce o^T and l, normalize, write y (bf16)
    // per-wave l: reduce over quads first (each lane then holds l[q=q4*16+ln])
    #pragma unroll
    for (int q4 = 0; q4 < 4; ++q4) {
        lac[q4] += __shfl_xor(lac[q4], 16);
        lac[q4] += __shfl_xor(lac[q4], 32);
    }

    const int qloc = 16 * w + (lane >> 2); // q-row this lane reduces
    float inv = 0.f;

    #pragma unroll
    for (int pass = 0; pass < 2; ++pass) { // d 0..31 then 32..63
        __syncthreads();                   // pass0 reads done (pass1) / entry
        #pragma unroll
        for (int db2 = 0; db2 < 2; ++db2)
            #pragma unroll
            for (int q4 = 0; q4 < 4; ++q4)
                *(f32x4*)&Ored[(w * 64 + q4 * 16 + ln) * 36 + db2 * 16 + quad * 4]
                    = o[pass * 2 + db2][q4];
        if (pass == 0 && quad == 0) {
            #pragma unroll
            for (int q4 = 0; q4 < 4; ++q4)
                Ored[(w * 64 + q4 * 16 + ln) * 36 + 32] = lac[q4];
        }
        __syncthreads();

        f32x4 a0 = (f32x4){0.f, 0.f, 0.f, 0.f};
        f32x4 a1 = (f32x4){0.f, 0.f, 0.f, 0.f};
        float ls = 0.f;
        #pragma unroll
        for (int v = 0; v < 4; ++v) {
            const int base = (v * 64 + qloc) * 36;
            a0 += *(const f32x4*)&Ored[base + (lane & 3) * 4];
            a1 += *(const f32x4*)&Ored[base + 16 + (lane & 3) * 4];
            if (pass == 0) ls += Ored[base + 32];
        }
        if (pass == 0) inv = 1.0f / ls;

        const int qg = qt * 64 + qloc;
        ushort* yrow = yb + ((size_t)b * T_N + qg) * C_N + h * HS_N
                       + pass * 32 + (lane & 3) * 4;
        ushort4 s0, s1;
        s0.x = f2bf(a0[0] * inv); s0.y = f2bf(a0[1] * inv);
        s0.z = f2bf(a0[2] * inv); s0.w = f2bf(a0[3] * inv);
        s1.x = f2bf(a1[0] * inv); s1.y = f2bf(a1[1] * inv);
        s1.z = f2bf(a1[2] * inv); s1.w = f2bf(a1[3] * inv);
        *(ushort4*)yrow = s0;
        *(ushort4*)(yrow + 16) = s1;
    }
}

// ---------------------------------------------------------------------------
extern "C" void kernel_launch(void* const* d_in, const int* in_sizes, int n_in,
                              void* d_out, int out_size, void* d_ws, size_t ws_size,
                              hipStream_t stream) {
    const float* x  = (const float*)d_in[0];
    const float* Wk = (const float*)d_in[1];
    const float* Wv = (const float*)d_in[2];
    const float* Wq = (const float*)d_in[3];
    const float* Wp = (const float*)d_in[4];
    const float* bp = (const float*)d_in[5];
    float* out = (float*)d_out;

    ushort* xb   = (ushort*)d_ws;                     // [4096][1024]
    ushort* qb   = xb   + (size_t)M_N * C_N;          // [4096][1024]
    ushort* yb   = qb   + (size_t)M_N * C_N;          // [4096][1024]
    ushort* kbw  = yb   + (size_t)M_N * C_N;          // kfrag, 4096*64
    ushort* vbt  = kbw  + (size_t)M_N * HS_N;         // vfrag, 2*64*2048
    ushort* Wqb  = vbt  + (size_t)B_N * HS_N * T_N;   // [1024][1024] (scaled)
    ushort* Wkvb = Wqb  + (size_t)C_N * C_N;          // [128][1024], after Wq
    ushort* Wpb  = Wkvb + (size_t)128 * C_N;          // [1024][1024]

    cvt_all_kernel<<<1024, 256, 0, stream>>>(x, Wq, Wp, Wk, Wv,
                                             xb, Wqb, Wpb, Wkvb);

    // fused q + k + v projection: W' = [Wq(scaled); Wk; Wv] (1152 rows)
    // n-tiles 0..7 -> qb; tile 8 -> kbw + vbt in fragment order
    gemm_bf16<1><<<dim3(M_N / 64, (C_N + 128) / 128), 256, 0, stream>>>(
        xb, Wqb, nullptr, qb, kbw, vbt, C_N);

    // attention -> yb bf16; key-split, zero-staging, 1024 blocks, 3 blk/CU
    attn_mfma_kernel<<<dim3(B_N * H_N, 32), 256, 0, stream>>>(qb, kbw, vbt, yb);

    // out = y @ Wp^T + bp -> fp32
    gemm_bf16<0><<<dim3(M_N / 64, C_N / 128), 256, 0, stream>>>(
        yb, Wpb, bp, out, nullptr, nullptr, C_N);
}

// Round 12
// 135.803 us; speedup vs baseline: 1.0664x; 1.0221x over previous
//
#include <hip/hip_runtime.h>
#include <cstddef>
#include <cstdint>

// Problem constants: B=2, T=2048, C=1024, H=16, hs=64
#define B_N 2
#define T_N 2048
#define C_N 1024
#define H_N 16
#define HS_N 64
#define M_N (B_N * T_N)   // 4096

typedef __attribute__((ext_vector_type(8))) short bf16x8;   // 8 bf16 = 4 VGPRs
typedef __attribute__((ext_vector_type(4))) float f32x4;
typedef __attribute__((ext_vector_type(4))) unsigned int u32x4;
typedef __attribute__((ext_vector_type(2))) unsigned int u32x2;

// 0.125 (hs^-0.5) * log2(e): folded into Wq so attention uses exp2 directly
#define QSCALE 0.18033688011112042f

__device__ __forceinline__ ushort f2bf(float f) {
    union { float f; uint32_t u; } v; v.f = f;
    uint32_t r = v.u + 0x7fffu + ((v.u >> 16) & 1u);   // round-nearest-even
    return (ushort)(r >> 16);
}
// truncating pack of two P-values (P in [0,1], rel err ~2^-9 — validated).
// NEW: single v_perm_b32 (D = {b.hi16, a.hi16}) instead of lshr+and+or —
// 16 instead of ~48 VALU slots per tile on the attn softmax path.
__device__ __forceinline__ unsigned pack2_trunc(float a, float b) {
    union { float f; uint32_t u; } x, y; x.f = a; y.f = b;
    return __builtin_amdgcn_perm(y.u, x.u, 0x07060302u);
}

// async global->LDS, 16B per lane; lds base must be wave-uniform
#define GLL16(g, l)                                                         \
    __builtin_amdgcn_global_load_lds(                                       \
        (const __attribute__((address_space(1))) unsigned int*)(g),         \
        (__attribute__((address_space(3))) unsigned int*)(l), 16, 0, 0)

// ---------------------------------------------------------------------------
// Fused fp32->bf16 convert: x | Wq(*QSCALE) | Wp | Wk | Wv (one launch).
// ---------------------------------------------------------------------------
__global__ void cvt_all_kernel(const float* __restrict__ x,
                               const float* __restrict__ Wq,
                               const float* __restrict__ Wp,
                               const float* __restrict__ Wk,
                               const float* __restrict__ Wv,
                               ushort* __restrict__ xb,
                               ushort* __restrict__ Wqb,
                               ushort* __restrict__ Wpb,
                               ushort* __restrict__ Wkvb) {
    const int S0 = M_N * C_N / 4;
    const int S1 = S0 + C_N * C_N / 4;
    const int S2 = S1 + C_N * C_N / 4;
    const int S3 = S2 + HS_N * C_N / 4;
    const int S4 = S3 + HS_N * C_N / 4;
    const int stride = gridDim.x * blockDim.x;
    for (int i = blockIdx.x * blockDim.x + threadIdx.x; i < S4; i += stride) {
        const float* src; ushort* dst; int j; float sc = 1.f;
        if (i < S0)      { src = x;  dst = xb;   j = i; }
        else if (i < S1) { src = Wq; dst = Wqb;  j = i - S0; sc = QSCALE; }
        else if (i < S2) { src = Wp; dst = Wpb;  j = i - S1; }
        else if (i < S3) { src = Wk; dst = Wkvb; j = i - S2; }
        else             { src = Wv; dst = Wkvb + HS_N * C_N; j = i - S3; }
        const float4 f = ((const float4*)src)[j];
        ushort4 o;
        o.x = f2bf(f.x * sc); o.y = f2bf(f.y * sc);
        o.z = f2bf(f.z * sc); o.w = f2bf(f.w * sc);
        ((ushort4*)dst)[j] = o;
    }
}

// ---------------------------------------------------------------------------
// bf16 MFMA GEMM — BM=64, BN=128, BK=64, 256 threads (4 waves 2x2, 32x64),
// 2-phase double-buffered k-loop (R8), __launch_bounds__(256,3) (R10).
// FROZEN at R11 state (best measured: 138.8us).
// MODE 1 kv tile writes kb/vbt in MFMA FRAGMENT ORDER (see attn):
//   kfrag[key,d]  flat = ((((key>>4)*2+(d>>5))*4+((d>>3)&3))*16+(key&15))*8+(d&7)
//   vfrag[t,d]    flat = ((((t>>5)*4+(d>>4))*4+((t>>3)&3))*16+(d&15))*8+(t&7)
// ---------------------------------------------------------------------------
template <int MODE>
__global__ __launch_bounds__(256, 3) void gemm_bf16(
    const ushort* __restrict__ A,   // [M][K] bf16
    const ushort* __restrict__ W,   // [Ntot][K] bf16
    const float* __restrict__ bias, // MODE 0 only
    void* __restrict__ Cout,        // [M][1024] fp32 (MODE 0) / bf16 (MODE 1)
    ushort* __restrict__ kb,        // MODE 1: kfrag order, 4096*64
    ushort* __restrict__ vbt,       // MODE 1: vfrag order, 2*64*2048
    int K)                          // must be a multiple of 128 (nk even)
{
    __shared__ __align__(16) ushort As0[64 * 64];    // 8 KB
    __shared__ __align__(16) ushort Bs0[128 * 64];   // 16 KB
    __shared__ __align__(16) ushort As1[64 * 64];    // 8 KB
    __shared__ __align__(16) ushort Bs1[128 * 64];   // 16 KB
    // XCD swizzle (gridDim.x == 64 == M/64)
    const int flat = blockIdx.x + (blockIdx.y << 6);
    const int m0 = (((flat & 7) << 3) | ((flat >> 3) & 7)) * 64;
    const int n0 = (flat >> 6) * 128;
    const int tid = threadIdx.x;
    const int wid = tid >> 6;
    const int lane = tid & 63;
    const int ln = lane & 15;
    const int quad = lane >> 4;
    const int wm = wid >> 1, wn = wid & 1;   // wave = rows wm*32+, cols wn*64+

    f32x4 acc[2][4];
    #pragma unroll
    for (int i = 0; i < 2; ++i)
        #pragma unroll
        for (int j = 0; j < 4; ++j)
            acc[i][j] = (f32x4){0.f, 0.f, 0.f, 0.f};

    const int srow = lane >> 3;          // 0..7 row within 8-row segment
    const int schk = (lane & 7) ^ srow;  // fetched chunk (row&7 == srow)

    // issue the 6 async GLL16 loads for k-tile k0 into (Asb, Bsb)
    auto stage = [&](ushort* Asb, ushort* Bsb, int k0) {
        #pragma unroll
        for (int t = 0; t < 2; ++t) {    // A: 8 segments of 8 rows
            const int seg = wid * 2 + t;
            GLL16(A + (size_t)(m0 + seg * 8 + srow) * K + k0 + schk * 8,
                  Asb + seg * 512);
        }
        #pragma unroll
        for (int t = 0; t < 4; ++t) {    // B: 16 segments of 8 rows
            const int seg = wid * 4 + t;
            GLL16(W + (size_t)(n0 + seg * 8 + srow) * K + k0 + schk * 8,
                  Bsb + seg * 512);
        }
    };

    // consume one staged k-tile
    auto compute = [&](const ushort* Asb, const ushort* Bsb) {
        #pragma unroll
        for (int hh = 0; hh < 2; ++hh) {
            bf16x8 af[2], bf[4];
            const int sw = ln & 7;
            #pragma unroll
            for (int i = 0; i < 2; ++i) {
                const int row = wm * 32 + i * 16 + ln;
                af[i] = *(const bf16x8*)&Asb[row * 64 + (((hh * 4 + quad) ^ sw) * 8)];
            }
            #pragma unroll
            for (int j = 0; j < 4; ++j) {
                const int row = wn * 64 + j * 16 + ln;
                bf[j] = *(const bf16x8*)&Bsb[row * 64 + (((hh * 4 + quad) ^ sw) * 8)];
            }
            #pragma unroll
            for (int i = 0; i < 2; ++i)
                #pragma unroll
                for (int j = 0; j < 4; ++j)
                    acc[i][j] = __builtin_amdgcn_mfma_f32_16x16x32_bf16(
                        af[i], bf[j], acc[i][j], 0, 0, 0);
        }
    };

    const int nk = K >> 6;               // 16 for K=1024 (even)
    stage(As0, Bs0, 0);
    __syncthreads();                     // buf0 resident
    for (int kt = 0; kt < nk; kt += 2) {
        if (kt + 1 < nk) stage(As1, Bs1, (kt + 1) << 6);
        compute(As0, Bs0);
        __syncthreads();                 // buf1 loads (in flight during compute) done
        if (kt + 1 >= nk) break;
        if (kt + 2 < nk) stage(As0, Bs0, (kt + 2) << 6);
        compute(As1, Bs1);
        __syncthreads();                 // buf0 loads done
    }

    if (MODE == 1 && n0 >= C_N) {        // kv tile: K cols 0..63, V 64..127
        #pragma unroll
        for (int i = 0; i < 2; ++i) {
            const int row0 = m0 + wm * 32 + i * 16 + quad * 4;
            #pragma unroll
            for (int j = 0; j < 4; ++j) {
                const int c2 = wn * 64 + j * 16 + ln;
                if (c2 >= 64) {
                    // vfrag: 4 regs = t0..t0+3 (same 8-chunk since t0%4==0)
                    const int d = c2 - 64;
                    const int b = row0 >> 11;
                    const int t0 = row0 & 2047;
                    const int flatv = ((((t0 >> 5) * 4 + (d >> 4)) * 4
                                       + ((t0 >> 3) & 3)) * 16 + (d & 15)) * 8
                                      + (t0 & 7);
                    ushort4 pk;
                    pk.x = f2bf(acc[i][j][0]); pk.y = f2bf(acc[i][j][1]);
                    pk.z = f2bf(acc[i][j][2]); pk.w = f2bf(acc[i][j][3]);
                    *(ushort4*)&vbt[(size_t)b * HS_N * T_N + flatv] = pk;
                } else {
                    #pragma unroll
                    for (int reg = 0; reg < 4; ++reg) {
                        const int key = row0 + reg;   // global 0..4095
                        kb[((((key >> 4) * 2 + (c2 >> 5)) * 4
                             + ((c2 >> 3) & 3)) * 16 + (key & 15)) * 8
                           + (c2 & 7)] = f2bf(acc[i][j][reg]);
                    }
                }
            }
        }
        return;
    }

    #pragma unroll
    for (int i = 0; i < 2; ++i) {
        #pragma unroll
        for (int j = 0; j < 4; ++j) {
            const int col = n0 + wn * 64 + j * 16 + ln;
            const float bv = (MODE == 0) ? bias[col] : 0.f;
            #pragma unroll
            for (int reg = 0; reg < 4; ++reg) {
                const int row = m0 + wm * 32 + i * 16 + quad * 4 + reg;
                const float v = acc[i][j][reg] + bv;
                if (MODE == 0)
                    ((float*)Cout)[(size_t)row * C_N + col] = v;
                else
                    ((ushort*)Cout)[(size_t)row * C_N + col] = f2bf(v);
            }
        }
    }
}

// ---------------------------------------------------------------------------
// Flash causal MQA attention — KEY-SPLIT, ZERO-STAGING, (256,3) (R11 form,
// best measured). NEW this round: v_perm pack (see pack2_trunc) — at 3
// waves/SIMD the k-loop is VALU-issue-bound (~350 slots/tile x 3 waves
// oversubscribes issue); pack was ~48 of those slots, now 16.
//
// K/V pre-swizzled into MFMA fragment order by gemm1 (coalesced 16B/lane
// L2 streams); no barriers, no LDS in the k-loop. LDS = 36KB epilogue only.
// Q uses the torch RAW-VIEW layout: Q[b,h,t,d] = qb[b*T*C + h*T*hs + t*hs + d].
// ---------------------------------------------------------------------------
__global__ __launch_bounds__(256, 3) void attn_mfma_kernel(
    const ushort* __restrict__ qb,
    const ushort* __restrict__ kb,    // kfrag order
    const ushort* __restrict__ vbt,   // vfrag order
    ushort* __restrict__ yb)
{
    __shared__ __align__(16) float Ored[4 * 64 * 36];   // 36 KB epilogue only

    const int bh = blockIdx.x;
    const int b = bh >> 4, h = bh & 15;
    const int yy = blockIdx.y;
    // balanced qt map: resident groups (yy, yy+8, yy+16, yy+24) have ~equal work
    const int qt = (yy < 8) ? 31 - yy : (yy < 16) ? yy - 8
                 : (yy < 24) ? 39 - yy : yy - 16;
    const int nkt = (qt >> 1) + 1;    // 128-key tiles
    const int qmax = qt * 64 + 63;

    const int tid = threadIdx.x;
    const int w = tid >> 6;           // wave id = key-slice owner
    const int lane = tid & 63;
    const int ln = lane & 15;
    const int quad = lane >> 4;

    // ---- Q fragments, held whole loop: qf[qb4][kc2], B-operand layout
    bf16x8 qf[4][2];
    {
        const ushort* qs_ = qb + (size_t)b * T_N * C_N
                          + (size_t)h * T_N * HS_N
                          + (size_t)(qt * 64) * HS_N;
        #pragma unroll
        for (int q4 = 0; q4 < 4; ++q4)
            #pragma unroll
            for (int kc = 0; kc < 2; ++kc)
                qf[q4][kc] = *(const bf16x8*)(qs_ + (q4 * 16 + ln) * HS_N
                                              + kc * 32 + quad * 8);
    }

    const ushort* vbb = vbt + (size_t)b * HS_N * T_N;

    f32x4 o[4][4];                    // [db][qb]  o^T[d][q] partial (this wave's keys)
    #pragma unroll
    for (int i = 0; i < 4; ++i)
        #pragma unroll
        for (int j = 0; j < 4; ++j)
            o[i][j] = (f32x4){0.f, 0.f, 0.f, 0.f};
    float lac[4] = {0.f, 0.f, 0.f, 0.f};

    for (int kt = 0; kt < nkt; ++kt) {
        const int k0 = kt * 128;
        const bool dg = (kt == nkt - 1);       // only last tile crosses the diagonal
        const int kw0 = k0 + w * 32;           // this wave's first key
        if (dg && kw0 > qmax) break;           // whole slice masked; last tile anyway

        // fragment loads: coalesced 16B/lane, L2-resident
        const int b16 = ((b * T_N + k0) >> 4) + w * 2;   // key16 for nt=0
        bf16x8 kf[2][2], vf[4];
        #pragma unroll
        for (int nt = 0; nt < 2; ++nt)
            #pragma unroll
            for (int kc = 0; kc < 2; ++kc)
                kf[nt][kc] = *(const bf16x8*)
                    &kb[((((b16 + nt) * 2 + kc) * 4 + quad) * 16 + ln) * 8];
        const int t32 = (k0 >> 5) + w;
        #pragma unroll
        for (int db = 0; db < 4; ++db)
            vf[db] = *(const bf16x8*)
                &vbb[(((t32 * 4 + db) * 4 + quad) * 16 + ln) * 8];

        // QK^T: sc[nt][qb] = S^T[key = kw0+nt*16+quad*4+reg][q = qt*64+q4*16+ln]
        f32x4 sc[2][4];
        #pragma unroll
        for (int nt = 0; nt < 2; ++nt)
            #pragma unroll
            for (int q4 = 0; q4 < 4; ++q4) {
                f32x4 s = (f32x4){0.f, 0.f, 0.f, 0.f};
                s = __builtin_amdgcn_mfma_f32_16x16x32_bf16(kf[nt][0], qf[q4][0], s, 0, 0, 0);
                s = __builtin_amdgcn_mfma_f32_16x16x32_bf16(kf[nt][1], qf[q4][1], s, 0, 0, 0);
                sc[nt][q4] = s;
            }

        // softmax + pack:  pk[nt][q4][hf] = bf16 pair for keys (quad*4+2hf, +1)
        unsigned pk[2][4][2];
        #pragma unroll
        for (int nt = 0; nt < 2; ++nt)
            #pragma unroll
            for (int q4 = 0; q4 < 4; ++q4) {
                f32x4 s = sc[nt][q4];
                if (dg) {
                    const int qg = qt * 64 + q4 * 16 + ln;
                    #pragma unroll
                    for (int reg = 0; reg < 4; ++reg) {
                        const int key = kw0 + nt * 16 + quad * 4 + reg;
                        if (key > qg) s[reg] = -1e30f;
                    }
                }
                const float p0 = __builtin_amdgcn_exp2f(s[0]);
                const float p1 = __builtin_amdgcn_exp2f(s[1]);
                const float p2 = __builtin_amdgcn_exp2f(s[2]);
                const float p3 = __builtin_amdgcn_exp2f(s[3]);
                lac[q4] += (p0 + p1) + (p2 + p3);
                pk[nt][q4][0] = pack2_trunc(p0, p1);
                pk[nt][q4][1] = pack2_trunc(p2, p3);
            }

        // in-register transpose (D-layout -> B-operand) + PV
        #pragma unroll
        for (int q4 = 0; q4 < 4; ++q4) {
            u32x2 ab0 = __builtin_amdgcn_permlane32_swap(pk[0][q4][0], pk[1][q4][0], false, false);
            u32x2 rs0 = __builtin_amdgcn_permlane16_swap(ab0[0], ab0[1], false, false);
            u32x2 ab1 = __builtin_amdgcn_permlane32_swap(pk[0][q4][1], pk[1][q4][1], false, false);
            u32x2 rs1 = __builtin_amdgcn_permlane16_swap(ab1[0], ab1[1], false, false);
            u32x4 pw;
            pw[0] = rs0[0]; pw[1] = rs1[0]; pw[2] = rs0[1]; pw[3] = rs1[1];
            const bf16x8 pf = __builtin_bit_cast(bf16x8, pw);
            #pragma unroll
            for (int db = 0; db < 4; ++db)
                o[db][q4] = __builtin_amdgcn_mfma_f32_16x16x32_bf16(
                    vf[db], pf, o[db][q4], 0, 0, 0);
        }
    }

    // ---- epilogue: cross-wave reduce o^T and l, normalize, write y (bf16)
    // per-wave l: reduce over quads first (each lane then holds l[q=q4*16+ln])
    #pragma unroll
    for (int q4 = 0; q4 < 4; ++q4) {
        lac[q4] += __shfl_xor(lac[q4], 16);
        lac[q4] += __shfl_xor(lac[q4], 32);
    }

    const int qloc = 16 * w + (lane >> 2); // q-row this lane reduces
    float inv = 0.f;

    #pragma unroll
    for (int pass = 0; pass < 2; ++pass) { // d 0..31 then 32..63
        __syncthreads();                   // pass0 reads done (pass1) / entry
        #pragma unroll
        for (int db2 = 0; db2 < 2; ++db2)
            #pragma unroll
            for (int q4 = 0; q4 < 4; ++q4)
                *(f32x4*)&Ored[(w * 64 + q4 * 16 + ln) * 36 + db2 * 16 + quad * 4]
                    = o[pass * 2 + db2][q4];
        if (pass == 0 && quad == 0) {
            #pragma unroll
            for (int q4 = 0; q4 < 4; ++q4)
                Ored[(w * 64 + q4 * 16 + ln) * 36 + 32] = lac[q4];
        }
        __syncthreads();

        f32x4 a0 = (f32x4){0.f, 0.f, 0.f, 0.f};
        f32x4 a1 = (f32x4){0.f, 0.f, 0.f, 0.f};
        float ls = 0.f;
        #pragma unroll
        for (int v = 0; v < 4; ++v) {
            const int base = (v * 64 + qloc) * 36;
            a0 += *(const f32x4*)&Ored[base + (lane & 3) * 4];
            a1 += *(const f32x4*)&Ored[base + 16 + (lane & 3) * 4];
            if (pass == 0) ls += Ored[base + 32];
        }
        if (pass == 0) inv = 1.0f / ls;

        const int qg = qt * 64 + qloc;
        ushort* yrow = yb + ((size_t)b * T_N + qg) * C_N + h * HS_N
                       + pass * 32 + (lane & 3) * 4;
        ushort4 s0, s1;
        s0.x = f2bf(a0[0] * inv); s0.y = f2bf(a0[1] * inv);
        s0.z = f2bf(a0[2] * inv); s0.w = f2bf(a0[3] * inv);
        s1.x = f2bf(a1[0] * inv); s1.y = f2bf(a1[1] * inv);
        s1.z = f2bf(a1[2] * inv); s1.w = f2bf(a1[3] * inv);
        *(ushort4*)yrow = s0;
        *(ushort4*)(yrow + 16) = s1;
    }
}

// ---------------------------------------------------------------------------
extern "C" void kernel_launch(void* const* d_in, const int* in_sizes, int n_in,
                              void* d_out, int out_size, void* d_ws, size_t ws_size,
                              hipStream_t stream) {
    const float* x  = (const float*)d_in[0];
    const float* Wk = (const float*)d_in[1];
    const float* Wv = (const float*)d_in[2];
    const float* Wq = (const float*)d_in[3];
    const float* Wp = (const float*)d_in[4];
    const float* bp = (const float*)d_in[5];
    float* out = (float*)d_out;

    ushort* xb   = (ushort*)d_ws;                     // [4096][1024]
    ushort* qb   = xb   + (size_t)M_N * C_N;          // [4096][1024]
    ushort* yb   = qb   + (size_t)M_N * C_N;          // [4096][1024]
    ushort* kbw  = yb   + (size_t)M_N * C_N;          // kfrag, 4096*64
    ushort* vbt  = kbw  + (size_t)M_N * HS_N;         // vfrag, 2*64*2048
    ushort* Wqb  = vbt  + (size_t)B_N * HS_N * T_N;   // [1024][1024] (scaled)
    ushort* Wkvb = Wqb  + (size_t)C_N * C_N;          // [128][1024], after Wq
    ushort* Wpb  = Wkvb + (size_t)128 * C_N;          // [1024][1024]

    cvt_all_kernel<<<1024, 256, 0, stream>>>(x, Wq, Wp, Wk, Wv,
                                             xb, Wqb, Wpb, Wkvb);

    // fused q + k + v projection: W' = [Wq(scaled); Wk; Wv] (1152 rows)
    // n-tiles 0..7 -> qb; tile 8 -> kbw + vbt in fragment order
    gemm_bf16<1><<<dim3(M_N / 64, (C_N + 128) / 128), 256, 0, stream>>>(
        xb, Wqb, nullptr, qb, kbw, vbt, C_N);

    // attention -> yb bf16; key-split, zero-staging, 1024 blocks, 3 blk/CU
    attn_mfma_kernel<<<dim3(B_N * H_N, 32), 256, 0, stream>>>(qb, kbw, vbt, yb);

    // out = y @ Wp^T + bp -> fp32
    gemm_bf16<0><<<dim3(M_N / 64, C_N / 128), 256, 0, stream>>>(
        yb, Wpb, bp, out, nullptr, nullptr, C_N);
}